// Round 1
// baseline (38326.212 us; speedup 1.0000x reference)
//
#include <hip/hip_runtime.h>
#include <cstdint>

#define NN   50000
#define TT   128
#define EE   1600000
#define CIN  16
#define CH   32
#define COUT 8

// ---------- helpers ----------
__device__ __forceinline__ float rlane(float v, int k) {
  return __int_as_float(__builtin_amdgcn_readlane(__float_as_int(v), k));
}
__device__ __forceinline__ float sigf(float x) {
  // safe: overflow -> inf -> 0 ; underflow -> 0 -> 1
  return 1.0f / (1.0f + __expf(-x));
}
__device__ __forceinline__ float tanh_fast(float x) {
  x = fminf(fmaxf(x, -30.0f), 30.0f);
  float e = __expf(2.0f * x);
  return (e - 1.0f) / (e + 1.0f);
}

// ---------- setup kernels ----------
// Detect whether edge_index buffer is int64 (high words all zero) or int32.
__global__ void k_flag(const int* __restrict__ idx, int* __restrict__ flag) {
  if (threadIdx.x == 0) {
    int m = 1;
    for (int i = 1; i <= 32; ++i)
      if (idx[2 * i + 1] != 0) m = 0;
    flag[0] = m;
  }
}

__global__ void k_zero_i(int* __restrict__ p, int n) {
  int i = blockIdx.x * blockDim.x + threadIdx.x;
  if (i < n) p[i] = 0;
}
__global__ void k_zero_f(float* __restrict__ p, int n) {
  int i = blockIdx.x * blockDim.x + threadIdx.x;
  if (i < n) p[i] = 0.0f;
}

__global__ void k_deg(const int* __restrict__ idx, int* __restrict__ deg_s,
                      int* __restrict__ deg_d, const int* __restrict__ flag) {
  int e = blockIdx.x * blockDim.x + threadIdx.x;
  if (e >= EE) return;
  int m = flag[0];
  int s = m ? idx[2 * e] : idx[e];
  int d = m ? idx[2 * (EE + e)] : idx[EE + e];
  atomicAdd(&deg_s[s], 1);
  atomicAdd(&deg_d[d], 1);
}

__global__ void k_dinv(const int* __restrict__ deg_s, float* __restrict__ dinv) {
  int i = blockIdx.x * blockDim.x + threadIdx.x;
  if (i < NN) {
    int d = deg_s[i];
    dinv[i] = (d > 0) ? rsqrtf((float)d) : 0.0f;
  }
}

// single-block exclusive scan of in-degrees -> row_ptr, cursor
__global__ void k_scan(const int* __restrict__ deg, int* __restrict__ row_ptr,
                       int* __restrict__ cursor) {
  __shared__ int part[1024];
  int tid = threadIdx.x;
  const int chunk = (NN + 1023) / 1024;
  int b = tid * chunk;
  int e = b + chunk; if (e > NN) e = NN;
  int s = 0;
  for (int j = b; j < e; ++j) s += deg[j];
  part[tid] = s;
  __syncthreads();
  for (int off = 1; off < 1024; off <<= 1) {
    int v = part[tid];
    int add = (tid >= off) ? part[tid - off] : 0;
    __syncthreads();
    part[tid] = v + add;
    __syncthreads();
  }
  int run = (tid > 0) ? part[tid - 1] : 0;
  for (int j = b; j < e; ++j) {
    row_ptr[j] = run; cursor[j] = run;
    run += deg[j];
  }
  if (tid == 1023) row_ptr[NN] = part[1023];
}

__global__ void k_fill(const int* __restrict__ idx, const float* __restrict__ dinv,
                       int* __restrict__ cursor, int* __restrict__ col,
                       float* __restrict__ wgt, const int* __restrict__ flag) {
  int e = blockIdx.x * blockDim.x + threadIdx.x;
  if (e >= EE) return;
  int m = flag[0];
  int s = m ? idx[2 * e] : idx[e];
  int d = m ? idx[2 * (EE + e)] : idx[EE + e];
  int p = atomicAdd(&cursor[d], 1);
  col[p] = s;
  wgt[p] = -dinv[s] * dinv[d];
}

// ---------- per-timestep kernels ----------
// wave = 1 node; lane = {g = z|r half, c = channel}; weights in registers.
__global__ __launch_bounds__(256) void k1(
    const float* __restrict__ Xt, const float* __restrict__ h,
    const int* __restrict__ row_ptr, const int* __restrict__ col,
    const float* __restrict__ wgt,
    const float* __restrict__ W_xz, const float* __restrict__ b_xz,
    const float* __restrict__ W_hz, const float* __restrict__ b_hz,
    const float* __restrict__ W_xr, const float* __restrict__ b_xr,
    const float* __restrict__ W_hr, const float* __restrict__ b_hr,
    float* __restrict__ Zb, float* __restrict__ hrb, float* __restrict__ AX) {
  const int lane = threadIdx.x & 63;
  const int g = lane >> 5;
  const int c = lane & 31;
  const int ci = c & 15;
  const int wid = (blockIdx.x * blockDim.x + threadIdx.x) >> 6;
  const int nw = (gridDim.x * blockDim.x) >> 6;

  const float* Wh = g ? W_hr : W_hz;  // [2][32][32]
  const float* Wx = g ? W_xr : W_xz;  // [2][16][32]
  float w0[CH], w1[CH];
#pragma unroll
  for (int k = 0; k < CH; ++k) {
    w0[k] = Wh[k * CH + c];
    w1[k] = Wh[CH * CH + k * CH + c];
  }
  float wx0[CIN], wx1[CIN];
#pragma unroll
  for (int k = 0; k < CIN; ++k) {
    wx0[k] = Wx[k * CH + c];
    wx1[k] = Wx[CIN * CH + k * CH + c];
  }
  const float bias = g ? (b_xr[c] + b_hr[c]) : (b_xz[c] + b_hz[c]);

  for (int i = wid; i < NN; i += nw) {
    const int iu = __builtin_amdgcn_readfirstlane(i);
    const float* hrow = h + (size_t)iu * CH;
    const float* xrow = Xt + (size_t)iu * CIN;
    float hv = hrow[c];
    int e0 = __builtin_amdgcn_readfirstlane(row_ptr[iu]);
    int e1 = __builtin_amdgcn_readfirstlane(row_ptr[iu + 1]);

    float ah0 = 0.f, ah1 = 0.f, ax0 = 0.f, ax1 = 0.f;
    int e = e0;
    for (; e + 2 <= e1; e += 2) {
      int sA = col[e], sB = col[e + 1];
      float wA = wgt[e], wB = wgt[e + 1];
      ah0 += wA * h[(size_t)sA * CH + c];
      ax0 += wA * Xt[(size_t)sA * CIN + ci];
      ah1 += wB * h[(size_t)sB * CH + c];
      ax1 += wB * Xt[(size_t)sB * CIN + ci];
    }
    if (e < e1) {
      int sA = col[e];
      float wA = wgt[e];
      ah0 += wA * h[(size_t)sA * CH + c];
      ax0 += wA * Xt[(size_t)sA * CIN + ci];
    }
    float ah = ah0 + ah1, ax = ax0 + ax1;

    float pa[4] = {0.f, 0.f, 0.f, 0.f};
#pragma unroll
    for (int k = 0; k < CH; ++k) {
      pa[k & 3] += hrow[k] * w0[k];
      pa[k & 3] += rlane(ah, k) * w1[k];
    }
#pragma unroll
    for (int k = 0; k < CIN; ++k) {
      pa[k & 3] += xrow[k] * wx0[k];
      pa[k & 3] += rlane(ax, k) * wx1[k];
    }
    float acc = bias + ((pa[0] + pa[1]) + (pa[2] + pa[3]));
    float sg = sigf(acc);
    if (g == 0) Zb[(size_t)iu * CH + c] = sg;       // Z gate
    else        hrb[(size_t)iu * CH + c] = hv * sg; // h * R
    if (lane < CIN) AX[(size_t)iu * CIN + lane] = ax;
  }
}

__global__ __launch_bounds__(256) void k2(
    const float* __restrict__ Xt, float* __restrict__ h,
    const int* __restrict__ row_ptr, const int* __restrict__ col,
    const float* __restrict__ wgt,
    const float* __restrict__ W_xh, const float* __restrict__ b_xh,
    const float* __restrict__ W_hh, const float* __restrict__ b_hh,
    const float* __restrict__ fc_w, const float* __restrict__ fc_b,
    const float* __restrict__ Zb, const float* __restrict__ hrb,
    const float* __restrict__ AX, float* __restrict__ outT) {
  const int lane = threadIdx.x & 63;
  const int g = lane >> 5;
  const int c = lane & 31;
  const int wid = (blockIdx.x * blockDim.x + threadIdx.x) >> 6;
  const int nw = (gridDim.x * blockDim.x) >> 6;

  float whh0[CH], whh1[CH];
#pragma unroll
  for (int k = 0; k < CH; ++k) {
    whh0[k] = W_hh[k * CH + c];
    whh1[k] = W_hh[CH * CH + k * CH + c];
  }
  float wxh0[CIN], wxh1[CIN];
#pragma unroll
  for (int k = 0; k < CIN; ++k) {
    wxh0[k] = W_xh[k * CH + c];
    wxh1[k] = W_xh[CIN * CH + k * CH + c];
  }
  float fcw[CH];
#pragma unroll
  for (int k = 0; k < CH; ++k) fcw[k] = fc_w[k * COUT + (c & 7)];
  const float bh = b_xh[c] + b_hh[c];
  const float fb = fc_b[c & 7];

  for (int i = wid; i < NN; i += nw) {
    const int iu = __builtin_amdgcn_readfirstlane(i);
    const float* hrow = h + (size_t)iu * CH;
    const float* hrrow = hrb + (size_t)iu * CH;
    const float* xrow = Xt + (size_t)iu * CIN;
    const float* axrow = AX + (size_t)iu * CIN;
    int e0 = __builtin_amdgcn_readfirstlane(row_ptr[iu]);
    int e1 = __builtin_amdgcn_readfirstlane(row_ptr[iu + 1]);

    float a0 = 0.f, a1 = 0.f;
    int e = e0;
    for (; e + 2 <= e1; e += 2) {
      int sA = col[e], sB = col[e + 1];
      float wA = wgt[e], wB = wgt[e + 1];
      a0 += wA * hrb[(size_t)sA * CH + c];
      a1 += wB * hrb[(size_t)sB * CH + c];
    }
    if (e < e1) {
      int sA = col[e];
      a0 += wgt[e] * hrb[(size_t)sA * CH + c];
    }
    float ahr = a0 + a1;

    float pa[4] = {0.f, 0.f, 0.f, 0.f};
#pragma unroll
    for (int k = 0; k < CIN; ++k) {
      pa[k & 3] += xrow[k] * wxh0[k];
      pa[k & 3] += axrow[k] * wxh1[k];
    }
#pragma unroll
    for (int k = 0; k < CH; ++k) {
      pa[k & 3] += hrrow[k] * whh0[k];
      pa[k & 3] += rlane(ahr, k) * whh1[k];
    }
    float acc = bh + ((pa[0] + pa[1]) + (pa[2] + pa[3]));
    float ht = tanh_fast(acc);
    float zv = Zb[(size_t)iu * CH + c];
    float hv = hrow[c];
    float hn = zv * hv + (1.0f - zv) * ht;
    if (g == 0) h[(size_t)iu * CH + c] = hn;

    float o0 = fb, o1 = 0.f;
#pragma unroll
    for (int k = 0; k < CH; k += 2) {
      o0 += rlane(hn, k) * fcw[k];
      o1 += rlane(hn, k + 1) * fcw[k + 1];
    }
    float o = o0 + o1;
    if (lane < COUT) outT[(size_t)iu * COUT + lane] = o;
  }
}

// ---------- host ----------
extern "C" void kernel_launch(void* const* d_in, const int* in_sizes, int n_in,
                              void* d_out, int out_size, void* d_ws, size_t ws_size,
                              hipStream_t stream) {
  const float* X = (const float*)d_in[0];
  const int* idx = (const int*)d_in[1];
  const float* W_xz = (const float*)d_in[2];  const float* b_xz = (const float*)d_in[3];
  const float* W_hz = (const float*)d_in[4];  const float* b_hz = (const float*)d_in[5];
  const float* W_xr = (const float*)d_in[6];  const float* b_xr = (const float*)d_in[7];
  const float* W_hr = (const float*)d_in[8];  const float* b_hr = (const float*)d_in[9];
  const float* W_xh = (const float*)d_in[10]; const float* b_xh = (const float*)d_in[11];
  const float* W_hh = (const float*)d_in[12]; const float* b_hh = (const float*)d_in[13];
  const float* fc_w = (const float*)d_in[14]; const float* fc_b = (const float*)d_in[15];
  float* out = (float*)d_out;

  char* ws = (char*)d_ws;
  size_t off = 0;
  auto alloc = [&](size_t bytes) -> void* {
    void* p = ws + off;
    off = (off + bytes + 255) & ~(size_t)255;
    return p;
  };
  int* flag = (int*)alloc(4);
  int* deg_s = (int*)alloc((size_t)NN * 4);
  int* deg_d = (int*)alloc((size_t)NN * 4);
  int* row_ptr = (int*)alloc((size_t)(NN + 1) * 4);
  int* cursor = (int*)alloc((size_t)NN * 4);
  float* dinv = (float*)alloc((size_t)NN * 4);
  int* col = (int*)alloc((size_t)EE * 4);
  float* wgt = (float*)alloc((size_t)EE * 4);
  float* h = (float*)alloc((size_t)NN * CH * 4);
  float* hrb = (float*)alloc((size_t)NN * CH * 4);
  float* Zb = (float*)alloc((size_t)NN * CH * 4);
  float* AX = (float*)alloc((size_t)NN * CIN * 4);

  k_flag<<<1, 64, 0, stream>>>(idx, flag);
  k_zero_i<<<(NN + 255) / 256, 256, 0, stream>>>(deg_s, NN);
  k_zero_i<<<(NN + 255) / 256, 256, 0, stream>>>(deg_d, NN);
  k_deg<<<(EE + 255) / 256, 256, 0, stream>>>(idx, deg_s, deg_d, flag);
  k_dinv<<<(NN + 255) / 256, 256, 0, stream>>>(deg_s, dinv);
  k_scan<<<1, 1024, 0, stream>>>(deg_d, row_ptr, cursor);
  k_fill<<<(EE + 255) / 256, 256, 0, stream>>>(idx, dinv, cursor, col, wgt, flag);
  k_zero_f<<<(NN * CH + 255) / 256, 256, 0, stream>>>(h, NN * CH);

  const int blocks = 1563;  // 6252 waves, ~8 nodes/wave grid-stride
  for (int t = 0; t < TT; ++t) {
    const float* Xt = X + (size_t)t * NN * CIN;
    float* outT = out + (size_t)t * NN * COUT;
    k1<<<blocks, 256, 0, stream>>>(Xt, h, row_ptr, col, wgt,
                                   W_xz, b_xz, W_hz, b_hz, W_xr, b_xr, W_hr, b_hr,
                                   Zb, hrb, AX);
    k2<<<blocks, 256, 0, stream>>>(Xt, h, row_ptr, col, wgt,
                                   W_xh, b_xh, W_hh, b_hh, fc_w, fc_b,
                                   Zb, hrb, AX, outT);
  }
}

// Round 2
// 26838.110 us; speedup vs baseline: 1.4281x; 1.4281x over previous
//
#include <hip/hip_runtime.h>
#include <cstdint>

#define NN   50000
#define TT   128
#define EE   1600000
#define CIN  16
#define CH   32
#define COUT 8

// ---------- helpers ----------
__device__ __forceinline__ float rlane(float v, int k) {
  return __int_as_float(__builtin_amdgcn_readlane(__float_as_int(v), k));
}
__device__ __forceinline__ float xhalf(float v) {  // add value from other 32-lane half
  return __shfl_xor(v, 32, 64);
}
__device__ __forceinline__ float sigf(float x) {
  return 1.0f / (1.0f + __expf(-x));
}
__device__ __forceinline__ float tanh_fast(float x) {
  x = fminf(fmaxf(x, -30.0f), 30.0f);
  float e = __expf(2.0f * x);
  return (e - 1.0f) / (e + 1.0f);
}

// ---------- setup kernels (unchanged from round 1, verified correct) ----------
__global__ void k_flag(const int* __restrict__ idx, int* __restrict__ flag) {
  if (threadIdx.x == 0) {
    int m = 1;
    for (int i = 1; i <= 32; ++i)
      if (idx[2 * i + 1] != 0) m = 0;
    flag[0] = m;
  }
}

__global__ void k_zero_i(int* __restrict__ p, int n) {
  int i = blockIdx.x * blockDim.x + threadIdx.x;
  if (i < n) p[i] = 0;
}
__global__ void k_zero_f(float* __restrict__ p, int n) {
  int i = blockIdx.x * blockDim.x + threadIdx.x;
  if (i < n) p[i] = 0.0f;
}

__global__ void k_deg(const int* __restrict__ idx, int* __restrict__ deg_s,
                      int* __restrict__ deg_d, const int* __restrict__ flag) {
  int e = blockIdx.x * blockDim.x + threadIdx.x;
  if (e >= EE) return;
  int m = flag[0];
  int s = m ? idx[2 * e] : idx[e];
  int d = m ? idx[2 * (EE + e)] : idx[EE + e];
  atomicAdd(&deg_s[s], 1);
  atomicAdd(&deg_d[d], 1);
}

__global__ void k_dinv(const int* __restrict__ deg_s, float* __restrict__ dinv) {
  int i = blockIdx.x * blockDim.x + threadIdx.x;
  if (i < NN) {
    int d = deg_s[i];
    dinv[i] = (d > 0) ? rsqrtf((float)d) : 0.0f;
  }
}

__global__ void k_scan(const int* __restrict__ deg, int* __restrict__ row_ptr,
                       int* __restrict__ cursor) {
  __shared__ int part[1024];
  int tid = threadIdx.x;
  const int chunk = (NN + 1023) / 1024;
  int b = tid * chunk;
  int e = b + chunk; if (e > NN) e = NN;
  int s = 0;
  for (int j = b; j < e; ++j) s += deg[j];
  part[tid] = s;
  __syncthreads();
  for (int off = 1; off < 1024; off <<= 1) {
    int v = part[tid];
    int add = (tid >= off) ? part[tid - off] : 0;
    __syncthreads();
    part[tid] = v + add;
    __syncthreads();
  }
  int run = (tid > 0) ? part[tid - 1] : 0;
  for (int j = b; j < e; ++j) {
    row_ptr[j] = run; cursor[j] = run;
    run += deg[j];
  }
  if (tid == 1023) row_ptr[NN] = part[1023];
}

__global__ void k_fill(const int* __restrict__ idx, const float* __restrict__ dinv,
                       int* __restrict__ cursor, int* __restrict__ col,
                       float* __restrict__ wgt, const int* __restrict__ flag) {
  int e = blockIdx.x * blockDim.x + threadIdx.x;
  if (e >= EE) return;
  int m = flag[0];
  int s = m ? idx[2 * e] : idx[e];
  int d = m ? idx[2 * (EE + e)] : idx[EE + e];
  int p = atomicAdd(&cursor[d], 1);
  col[p] = s;
  wgt[p] = -dinv[s] * dinv[d];
}

// ---------- per-timestep kernels ----------
// All: wave = 1 node (grid-stride, 4 nodes/wave); lane = {g = half, c = channel}.
// Edge list split contiguously across halves; partials combined via shfl_xor(32).

// kx: x-side contributions for all 3 gates -> Gx[n][96] (biases folded in).
__global__ __launch_bounds__(256, 4) void kx(
    const float* __restrict__ Xt,
    const int* __restrict__ row_ptr, const int* __restrict__ col,
    const float* __restrict__ wgt,
    const float* __restrict__ W_xz, const float* __restrict__ b_xz,
    const float* __restrict__ b_hz,
    const float* __restrict__ W_xr, const float* __restrict__ b_xr,
    const float* __restrict__ b_hr,
    const float* __restrict__ W_xh, const float* __restrict__ b_xh,
    const float* __restrict__ b_hh,
    float* __restrict__ Gx) {
  const int lane = threadIdx.x & 63;
  const int g = lane >> 5;
  const int c = lane & 31;
  const int ci = c & 15;
  const int wid = (blockIdx.x * blockDim.x + threadIdx.x) >> 6;
  const int nw = (gridDim.x * blockDim.x) >> 6;

  const float* Wzr = g ? W_xr : W_xz;   // [2][16][32]
  float w0[CIN], w1[CIN], wh0[CIN], wh1[CIN];
#pragma unroll
  for (int k = 0; k < CIN; ++k) {
    w0[k]  = Wzr[k * CH + c];
    w1[k]  = Wzr[CIN * CH + k * CH + c];
    wh0[k] = W_xh[k * CH + c];
    wh1[k] = W_xh[CIN * CH + k * CH + c];
  }
  const float bzr = g ? (b_xr[c] + b_hr[c]) : (b_xz[c] + b_hz[c]);
  const float bh  = b_xh[c] + b_hh[c];

  for (int i = wid; i < NN; i += nw) {
    const int iu = __builtin_amdgcn_readfirstlane(i);
    const int e0 = __builtin_amdgcn_readfirstlane(row_ptr[iu]);
    const int e1 = __builtin_amdgcn_readfirstlane(row_ptr[iu + 1]);
    const int deg = e1 - e0;
    const int len0 = (deg + 1) >> 1;
    const int s = e0 + (g ? len0 : 0);
    const int send = g ? e1 : (e0 + len0);

    float a0 = 0.f, a1 = 0.f, a2 = 0.f, a3 = 0.f;
    int j = s;
    for (; j + 4 <= send; j += 4) {
      int s0 = col[j], s1 = col[j + 1], s2 = col[j + 2], s3 = col[j + 3];
      float wA = wgt[j], wB = wgt[j + 1], wC = wgt[j + 2], wD = wgt[j + 3];
      a0 += wA * Xt[s0 * CIN + ci];
      a1 += wB * Xt[s1 * CIN + ci];
      a2 += wC * Xt[s2 * CIN + ci];
      a3 += wD * Xt[s3 * CIN + ci];
    }
    for (; j < send; ++j)
      a0 += wgt[j] * Xt[col[j] * CIN + ci];
    float axh = (a0 + a1) + (a2 + a3);
    float ax = axh + xhalf(axh);   // full agg(x)[ci]

    const float* xrow = Xt + (size_t)iu * CIN;
    float accA = bzr, accH = bh;
#pragma unroll
    for (int k = 0; k < CIN; ++k) {
      float xk = xrow[k];
      float axk = rlane(ax, k);
      accA += xk * w0[k] + axk * w1[k];
      accH += xk * wh0[k] + axk * wh1[k];
    }
    float* grow = Gx + (size_t)iu * 96;
    grow[g * CH + c] = accA;          // z at [0:32), r at [32:64)
    if (g == 0) grow[64 + c] = accH;  // h-candidate x-part
  }
}

// k1: agg(h) -> Z gate, h*R
__global__ __launch_bounds__(256, 4) void k1(
    const float* __restrict__ h,
    const int* __restrict__ row_ptr, const int* __restrict__ col,
    const float* __restrict__ wgt,
    const float* __restrict__ W_hz, const float* __restrict__ W_hr,
    const float* __restrict__ Gx,
    float* __restrict__ Zb, float* __restrict__ hrb) {
  const int lane = threadIdx.x & 63;
  const int g = lane >> 5;
  const int c = lane & 31;
  const int wid = (blockIdx.x * blockDim.x + threadIdx.x) >> 6;
  const int nw = (gridDim.x * blockDim.x) >> 6;

  const float* Wh = g ? W_hr : W_hz;  // [2][32][32]
  float w0[CH], w1[CH];
#pragma unroll
  for (int k = 0; k < CH; ++k) {
    w0[k] = Wh[k * CH + c];
    w1[k] = Wh[CH * CH + k * CH + c];
  }

  for (int i = wid; i < NN; i += nw) {
    const int iu = __builtin_amdgcn_readfirstlane(i);
    const int e0 = __builtin_amdgcn_readfirstlane(row_ptr[iu]);
    const int e1 = __builtin_amdgcn_readfirstlane(row_ptr[iu + 1]);
    const int deg = e1 - e0;
    const int len0 = (deg + 1) >> 1;
    const int s = e0 + (g ? len0 : 0);
    const int send = g ? e1 : (e0 + len0);

    float a0 = 0.f, a1 = 0.f, a2 = 0.f, a3 = 0.f;
    int j = s;
    for (; j + 4 <= send; j += 4) {
      int s0 = col[j], s1 = col[j + 1], s2 = col[j + 2], s3 = col[j + 3];
      float wA = wgt[j], wB = wgt[j + 1], wC = wgt[j + 2], wD = wgt[j + 3];
      a0 += wA * h[s0 * CH + c];
      a1 += wB * h[s1 * CH + c];
      a2 += wC * h[s2 * CH + c];
      a3 += wD * h[s3 * CH + c];
    }
    for (; j < send; ++j)
      a0 += wgt[j] * h[col[j] * CH + c];
    float ahh = (a0 + a1) + (a2 + a3);
    float ah = ahh + xhalf(ahh);    // full agg(h)[c]

    const float* hrow = h + (size_t)iu * CH;
    float acc = Gx[(size_t)iu * 96 + g * CH + c];
#pragma unroll
    for (int k = 0; k < CH; ++k) {
      float hk = hrow[k];
      float ahk = rlane(ah, k);
      acc += hk * w0[k] + ahk * w1[k];
    }
    float sg = sigf(acc);
    float hv = hrow[c];
    if (g == 0) Zb[(size_t)iu * CH + c] = sg;
    else        hrb[(size_t)iu * CH + c] = hv * sg;
  }
}

// k2: agg(h*R) -> candidate, h update, fused FC output
__global__ __launch_bounds__(256, 4) void k2(
    float* __restrict__ h, const float* __restrict__ hrb,
    const int* __restrict__ row_ptr, const int* __restrict__ col,
    const float* __restrict__ wgt,
    const float* __restrict__ W_hh,
    const float* __restrict__ fc_w, const float* __restrict__ fc_b,
    const float* __restrict__ Gx, const float* __restrict__ Zb,
    float* __restrict__ outT) {
  const int lane = threadIdx.x & 63;
  const int g = lane >> 5;
  const int c = lane & 31;
  const int wid = (blockIdx.x * blockDim.x + threadIdx.x) >> 6;
  const int nw = (gridDim.x * blockDim.x) >> 6;

  float w0[CH], w1[CH], fcw[CH];
#pragma unroll
  for (int k = 0; k < CH; ++k) {
    w0[k] = W_hh[k * CH + c];
    w1[k] = W_hh[CH * CH + k * CH + c];
    fcw[k] = fc_w[k * COUT + (c & 7)];
  }
  const float fb = fc_b[c & 7];

  for (int i = wid; i < NN; i += nw) {
    const int iu = __builtin_amdgcn_readfirstlane(i);
    const int e0 = __builtin_amdgcn_readfirstlane(row_ptr[iu]);
    const int e1 = __builtin_amdgcn_readfirstlane(row_ptr[iu + 1]);
    const int deg = e1 - e0;
    const int len0 = (deg + 1) >> 1;
    const int s = e0 + (g ? len0 : 0);
    const int send = g ? e1 : (e0 + len0);

    float a0 = 0.f, a1 = 0.f, a2 = 0.f, a3 = 0.f;
    int j = s;
    for (; j + 4 <= send; j += 4) {
      int s0 = col[j], s1 = col[j + 1], s2 = col[j + 2], s3 = col[j + 3];
      float wA = wgt[j], wB = wgt[j + 1], wC = wgt[j + 2], wD = wgt[j + 3];
      a0 += wA * hrb[s0 * CH + c];
      a1 += wB * hrb[s1 * CH + c];
      a2 += wC * hrb[s2 * CH + c];
      a3 += wD * hrb[s3 * CH + c];
    }
    for (; j < send; ++j)
      a0 += wgt[j] * hrb[col[j] * CH + c];
    float ahh = (a0 + a1) + (a2 + a3);
    float ahr = ahh + xhalf(ahh);   // full agg(h*R)[c]

    const float* hrrow = hrb + (size_t)iu * CH;
    const float* hrow = h + (size_t)iu * CH;
    float acc = Gx[(size_t)iu * 96 + 64 + c];
#pragma unroll
    for (int k = 0; k < CH; ++k) {
      float hk = hrrow[k];
      float ahk = rlane(ahr, k);
      acc += hk * w0[k] + ahk * w1[k];
    }
    float ht = tanh_fast(acc);
    float zv = Zb[(size_t)iu * CH + c];
    float hv = hrow[c];
    float hn = zv * hv + (1.0f - zv) * ht;   // identical in both halves
    if (g == 0) h[(size_t)iu * CH + c] = hn;

    float o0 = fb, o1 = 0.f;
#pragma unroll
    for (int k = 0; k < CH; k += 2) {
      o0 += rlane(hn, k) * fcw[k];
      o1 += rlane(hn, k + 1) * fcw[k + 1];
    }
    float o = o0 + o1;
    if (lane < COUT) outT[(size_t)iu * COUT + lane] = o;
  }
}

// ---------- host ----------
extern "C" void kernel_launch(void* const* d_in, const int* in_sizes, int n_in,
                              void* d_out, int out_size, void* d_ws, size_t ws_size,
                              hipStream_t stream) {
  const float* X = (const float*)d_in[0];
  const int* idx = (const int*)d_in[1];
  const float* W_xz = (const float*)d_in[2];  const float* b_xz = (const float*)d_in[3];
  const float* W_hz = (const float*)d_in[4];  const float* b_hz = (const float*)d_in[5];
  const float* W_xr = (const float*)d_in[6];  const float* b_xr = (const float*)d_in[7];
  const float* W_hr = (const float*)d_in[8];  const float* b_hr = (const float*)d_in[9];
  const float* W_xh = (const float*)d_in[10]; const float* b_xh = (const float*)d_in[11];
  const float* W_hh = (const float*)d_in[12]; const float* b_hh = (const float*)d_in[13];
  const float* fc_w = (const float*)d_in[14]; const float* fc_b = (const float*)d_in[15];
  float* out = (float*)d_out;

  char* ws = (char*)d_ws;
  size_t off = 0;
  auto alloc = [&](size_t bytes) -> void* {
    void* p = ws + off;
    off = (off + bytes + 255) & ~(size_t)255;
    return p;
  };
  int* flag = (int*)alloc(4);
  int* deg_s = (int*)alloc((size_t)NN * 4);
  int* deg_d = (int*)alloc((size_t)NN * 4);
  int* row_ptr = (int*)alloc((size_t)(NN + 1) * 4);
  int* cursor = (int*)alloc((size_t)NN * 4);
  float* dinv = (float*)alloc((size_t)NN * 4);
  int* col = (int*)alloc((size_t)EE * 4);
  float* wgt = (float*)alloc((size_t)EE * 4);
  float* h = (float*)alloc((size_t)NN * CH * 4);
  float* hrb = (float*)alloc((size_t)NN * CH * 4);
  float* Zb = (float*)alloc((size_t)NN * CH * 4);
  float* Gx = (float*)alloc((size_t)NN * 96 * 4);

  k_flag<<<1, 64, 0, stream>>>(idx, flag);
  k_zero_i<<<(NN + 255) / 256, 256, 0, stream>>>(deg_s, NN);
  k_zero_i<<<(NN + 255) / 256, 256, 0, stream>>>(deg_d, NN);
  k_deg<<<(EE + 255) / 256, 256, 0, stream>>>(idx, deg_s, deg_d, flag);
  k_dinv<<<(NN + 255) / 256, 256, 0, stream>>>(deg_s, dinv);
  k_scan<<<1, 1024, 0, stream>>>(deg_d, row_ptr, cursor);
  k_fill<<<(EE + 255) / 256, 256, 0, stream>>>(idx, dinv, cursor, col, wgt, flag);
  k_zero_f<<<(NN * CH + 255) / 256, 256, 0, stream>>>(h, NN * CH);

  // 12500 waves, 4 nodes/wave grid-stride: amortizes weight preload,
  // keeps ~16-20 waves/CU resident for gather-latency hiding.
  const int blocks = 3125;
  for (int t = 0; t < TT; ++t) {
    const float* Xt = X + (size_t)t * NN * CIN;
    float* outT = out + (size_t)t * NN * COUT;
    kx<<<blocks, 256, 0, stream>>>(Xt, row_ptr, col, wgt,
                                   W_xz, b_xz, b_hz, W_xr, b_xr, b_hr,
                                   W_xh, b_xh, b_hh, Gx);
    k1<<<blocks, 256, 0, stream>>>(h, row_ptr, col, wgt, W_hz, W_hr, Gx, Zb, hrb);
    k2<<<blocks, 256, 0, stream>>>(h, hrb, row_ptr, col, wgt, W_hh,
                                   fc_w, fc_b, Gx, Zb, outT);
  }
}

// Round 3
// 25411.421 us; speedup vs baseline: 1.5082x; 1.0561x over previous
//
#include <hip/hip_runtime.h>
#include <cstdint>

#define NN   50000
#define TT   128
#define EE   1600000
#define CIN  16
#define CH   32
#define COUT 8

// ---------- helpers ----------
__device__ __forceinline__ float rlane(float v, int k) {
  return __int_as_float(__builtin_amdgcn_readlane(__float_as_int(v), k));
}
__device__ __forceinline__ float xhalf(float v) {  // add value from other 32-lane half
  return __shfl_xor(v, 32, 64);
}
__device__ __forceinline__ float sigf(float x) {
  return 1.0f / (1.0f + __expf(-x));
}
__device__ __forceinline__ float tanh_fast(float x) {
  x = fminf(fmaxf(x, -30.0f), 30.0f);
  float e = __expf(2.0f * x);
  return (e - 1.0f) / (e + 1.0f);
}

// clamped 16-window CSR aggregation over rows of mat[*][CH], edge list split
// across wave halves; returns the FULL aggregate (both halves combined).
__device__ __forceinline__ float agg16(const float* __restrict__ mat,
                                       const int* __restrict__ col,
                                       const float* __restrict__ wgt,
                                       int e0, int e1, int g, int c) {
  const int deg = e1 - e0;
  const int len0 = (deg + 1) >> 1;
  const int s = e0 + (g ? len0 : 0);
  const int send = g ? e1 : (e0 + len0);
  float a[4] = {0.f, 0.f, 0.f, 0.f};
  int j = s;
  while (j < send) {
    int cidx[16];
    float wv[16];
#pragma unroll
    for (int k = 0; k < 16; ++k) {
      int jk = j + k;
      int sj = (jk < send) ? jk : (send - 1);
      cidx[k] = col[sj];
      wv[k] = (jk < send) ? wgt[sj] : 0.0f;
    }
#pragma unroll
    for (int k = 0; k < 16; ++k)
      a[k & 3] += wv[k] * mat[(size_t)cidx[k] * CH + c];
    j += 16;
  }
  float p = (a[0] + a[1]) + (a[2] + a[3]);
  return p + xhalf(p);
}

// ---------- setup kernels (verified rounds 1-2) ----------
__global__ void k_flag(const int* __restrict__ idx, int* __restrict__ flag) {
  if (threadIdx.x == 0) {
    int m = 1;
    for (int i = 1; i <= 32; ++i)
      if (idx[2 * i + 1] != 0) m = 0;
    flag[0] = m;
  }
}

__global__ void k_zero_i(int* __restrict__ p, int n) {
  int i = blockIdx.x * blockDim.x + threadIdx.x;
  if (i < n) p[i] = 0;
}
__global__ void k_zero_f(float* __restrict__ p, int n) {
  int i = blockIdx.x * blockDim.x + threadIdx.x;
  if (i < n) p[i] = 0.0f;
}

__global__ void k_deg(const int* __restrict__ idx, int* __restrict__ deg_s,
                      int* __restrict__ deg_d, const int* __restrict__ flag) {
  int e = blockIdx.x * blockDim.x + threadIdx.x;
  if (e >= EE) return;
  int m = flag[0];
  int s = m ? idx[2 * e] : idx[e];
  int d = m ? idx[2 * (EE + e)] : idx[EE + e];
  atomicAdd(&deg_s[s], 1);
  atomicAdd(&deg_d[d], 1);
}

__global__ void k_dinv(const int* __restrict__ deg_s, float* __restrict__ dinv) {
  int i = blockIdx.x * blockDim.x + threadIdx.x;
  if (i < NN) {
    int d = deg_s[i];
    dinv[i] = (d > 0) ? rsqrtf((float)d) : 0.0f;
  }
}

__global__ void k_scan(const int* __restrict__ deg, int* __restrict__ row_ptr,
                       int* __restrict__ cursor) {
  __shared__ int part[1024];
  int tid = threadIdx.x;
  const int chunk = (NN + 1023) / 1024;
  int b = tid * chunk;
  int e = b + chunk; if (e > NN) e = NN;
  int s = 0;
  for (int j = b; j < e; ++j) s += deg[j];
  part[tid] = s;
  __syncthreads();
  for (int off = 1; off < 1024; off <<= 1) {
    int v = part[tid];
    int add = (tid >= off) ? part[tid - off] : 0;
    __syncthreads();
    part[tid] = v + add;
    __syncthreads();
  }
  int run = (tid > 0) ? part[tid - 1] : 0;
  for (int j = b; j < e; ++j) {
    row_ptr[j] = run; cursor[j] = run;
    run += deg[j];
  }
  if (tid == 1023) row_ptr[NN] = part[1023];
}

__global__ void k_fill(const int* __restrict__ idx, const float* __restrict__ dinv,
                       int* __restrict__ cursor, int* __restrict__ col,
                       float* __restrict__ wgt, const int* __restrict__ flag) {
  int e = blockIdx.x * blockDim.x + threadIdx.x;
  if (e >= EE) return;
  int m = flag[0];
  int s = m ? idx[2 * e] : idx[e];
  int d = m ? idx[2 * (EE + e)] : idx[EE + e];
  int p = atomicAdd(&cursor[d], 1);
  col[p] = s;
  wgt[p] = -dinv[s] * dinv[d];
}

// ---------- x-side ----------
// kx_all: batched over ALL timesteps (t-quads). wave = 1 node, 4 consecutive t.
// Writes Gx[t][n][96] = x-contributions for z | r | candidate (biases folded).
__global__ __launch_bounds__(256, 3) void kx_all(
    const float* __restrict__ X,
    const int* __restrict__ row_ptr, const int* __restrict__ col,
    const float* __restrict__ wgt,
    const float* __restrict__ W_xz, const float* __restrict__ b_xz,
    const float* __restrict__ b_hz,
    const float* __restrict__ W_xr, const float* __restrict__ b_xr,
    const float* __restrict__ b_hr,
    const float* __restrict__ W_xh, const float* __restrict__ b_xh,
    const float* __restrict__ b_hh,
    float* __restrict__ Gx) {
  const int lane = threadIdx.x & 63;
  const int g = lane >> 5;
  const int c = lane & 31;
  const int ci = c & 15;
  const int tq = blockIdx.x / 12500;            // t-quad (32 of them)
  const int t0 = tq * 4;
  const int node = (blockIdx.x % 12500) * 4 + (threadIdx.x >> 6);
  const int iu = __builtin_amdgcn_readfirstlane(node);

  const float* Wzr = g ? W_xr : W_xz;           // [2][16][32]
  float w0[CIN], w1[CIN], wh0[CIN], wh1[CIN];
#pragma unroll
  for (int k = 0; k < CIN; ++k) {
    w0[k]  = Wzr[k * CH + c];
    w1[k]  = Wzr[CIN * CH + k * CH + c];
    wh0[k] = W_xh[k * CH + c];
    wh1[k] = W_xh[CIN * CH + k * CH + c];
  }
  const float bzr = g ? (b_xr[c] + b_hr[c]) : (b_xz[c] + b_hz[c]);
  const float bh  = b_xh[c] + b_hh[c];

  const int e0 = __builtin_amdgcn_readfirstlane(row_ptr[iu]);
  const int e1 = __builtin_amdgcn_readfirstlane(row_ptr[iu + 1]);
  const int deg = e1 - e0;
  const int len0 = (deg + 1) >> 1;
  const int s = e0 + (g ? len0 : 0);
  const int send = g ? e1 : (e0 + len0);

  float ax4[4] = {0.f, 0.f, 0.f, 0.f};
  int j = s;
  for (; j + 4 <= send; j += 4) {
    int c0 = col[j], c1 = col[j + 1], c2 = col[j + 2], c3 = col[j + 3];
    float wA = wgt[j], wB = wgt[j + 1], wC = wgt[j + 2], wD = wgt[j + 3];
#pragma unroll
    for (int tp = 0; tp < 4; ++tp) {
      const float* Xt = X + (size_t)(t0 + tp) * NN * CIN;
      ax4[tp] += wA * Xt[c0 * CIN + ci] + wB * Xt[c1 * CIN + ci]
               + wC * Xt[c2 * CIN + ci] + wD * Xt[c3 * CIN + ci];
    }
  }
  for (; j < send; ++j) {
    int cs = col[j];
    float wv = wgt[j];
#pragma unroll
    for (int tp = 0; tp < 4; ++tp)
      ax4[tp] += wv * (X + (size_t)(t0 + tp) * NN * CIN)[cs * CIN + ci];
  }
#pragma unroll
  for (int tp = 0; tp < 4; ++tp)
    ax4[tp] += xhalf(ax4[tp]);    // full agg(x_t)[ci]

#pragma unroll
  for (int tp = 0; tp < 4; ++tp) {
    const float* xrow = X + ((size_t)(t0 + tp) * NN + iu) * CIN;
    float accA = bzr, accH = bh;
#pragma unroll
    for (int k = 0; k < CIN; ++k) {
      float xk = xrow[k];
      float axk = rlane(ax4[tp], k);
      accA += xk * w0[k] + axk * w1[k];
      accH += xk * wh0[k] + axk * wh1[k];
    }
    float* grow = Gx + ((size_t)(t0 + tp) * NN + iu) * 96;
    grow[g * CH + c] = accA;
    if (g == 0) grow[64 + c] = accH;
  }
}

// kx: per-step fallback when ws too small for Gx-all (round-2 logic).
__global__ __launch_bounds__(256, 4) void kx(
    const float* __restrict__ Xt,
    const int* __restrict__ row_ptr, const int* __restrict__ col,
    const float* __restrict__ wgt,
    const float* __restrict__ W_xz, const float* __restrict__ b_xz,
    const float* __restrict__ b_hz,
    const float* __restrict__ W_xr, const float* __restrict__ b_xr,
    const float* __restrict__ b_hr,
    const float* __restrict__ W_xh, const float* __restrict__ b_xh,
    const float* __restrict__ b_hh,
    float* __restrict__ Gx) {
  const int lane = threadIdx.x & 63;
  const int g = lane >> 5;
  const int c = lane & 31;
  const int ci = c & 15;
  const int wid = (blockIdx.x * blockDim.x + threadIdx.x) >> 6;
  const int nw = (gridDim.x * blockDim.x) >> 6;

  const float* Wzr = g ? W_xr : W_xz;
  float w0[CIN], w1[CIN], wh0[CIN], wh1[CIN];
#pragma unroll
  for (int k = 0; k < CIN; ++k) {
    w0[k]  = Wzr[k * CH + c];
    w1[k]  = Wzr[CIN * CH + k * CH + c];
    wh0[k] = W_xh[k * CH + c];
    wh1[k] = W_xh[CIN * CH + k * CH + c];
  }
  const float bzr = g ? (b_xr[c] + b_hr[c]) : (b_xz[c] + b_hz[c]);
  const float bh  = b_xh[c] + b_hh[c];

  for (int i = wid; i < NN; i += nw) {
    const int iu = __builtin_amdgcn_readfirstlane(i);
    const int e0 = __builtin_amdgcn_readfirstlane(row_ptr[iu]);
    const int e1 = __builtin_amdgcn_readfirstlane(row_ptr[iu + 1]);
    // CIN-row aggregation via agg16 on a CIN-strided matrix is not directly
    // reusable (stride CH); do a clamped window inline with CIN stride.
    const int deg = e1 - e0;
    const int len0 = (deg + 1) >> 1;
    const int s = e0 + (g ? len0 : 0);
    const int send = g ? e1 : (e0 + len0);
    float a[4] = {0.f, 0.f, 0.f, 0.f};
    int j = s;
    while (j < send) {
      int cidx[16]; float wv[16];
#pragma unroll
      for (int k = 0; k < 16; ++k) {
        int jk = j + k;
        int sj = (jk < send) ? jk : (send - 1);
        cidx[k] = col[sj];
        wv[k] = (jk < send) ? wgt[sj] : 0.0f;
      }
#pragma unroll
      for (int k = 0; k < 16; ++k)
        a[k & 3] += wv[k] * Xt[(size_t)cidx[k] * CIN + ci];
      j += 16;
    }
    float axh = (a[0] + a[1]) + (a[2] + a[3]);
    float ax = axh + xhalf(axh);

    const float* xrow = Xt + (size_t)iu * CIN;
    float accA = bzr, accH = bh;
#pragma unroll
    for (int k = 0; k < CIN; ++k) {
      float xk = xrow[k];
      float axk = rlane(ax, k);
      accA += xk * w0[k] + axk * w1[k];
      accH += xk * wh0[k] + axk * wh1[k];
    }
    float* grow = Gx + (size_t)iu * 96;
    grow[g * CH + c] = accA;
    if (g == 0) grow[64 + c] = accH;
  }
}

// ---------- recurrent kernels ----------
// k1: agg(h) -> Z gate, h*R. Gxt = x-contribution slab for this t.
__global__ __launch_bounds__(256, 3) void k1(
    const float* __restrict__ h,
    const int* __restrict__ row_ptr, const int* __restrict__ col,
    const float* __restrict__ wgt,
    const float* __restrict__ W_hz, const float* __restrict__ W_hr,
    const float* __restrict__ Gxt,
    float* __restrict__ Zb, float* __restrict__ hrb) {
  const int lane = threadIdx.x & 63;
  const int g = lane >> 5;
  const int c = lane & 31;
  const int wid = (blockIdx.x * blockDim.x + threadIdx.x) >> 6;
  const int nw = (gridDim.x * blockDim.x) >> 6;

  const float* Wh = g ? W_hr : W_hz;  // [2][32][32]
  float w0[CH], w1[CH];
#pragma unroll
  for (int k = 0; k < CH; ++k) {
    w0[k] = Wh[k * CH + c];
    w1[k] = Wh[CH * CH + k * CH + c];
  }

  for (int i = wid * 2; i < NN; i += nw * 2) {
#pragma unroll
    for (int u = 0; u < 2; ++u) {
      const int iu = __builtin_amdgcn_readfirstlane(i + u);
      const int e0 = __builtin_amdgcn_readfirstlane(row_ptr[iu]);
      const int e1 = __builtin_amdgcn_readfirstlane(row_ptr[iu + 1]);
      float ah = agg16(h, col, wgt, e0, e1, g, c);

      const float* hrow = h + (size_t)iu * CH;
      float acc = Gxt[(size_t)iu * 96 + g * CH + c];
#pragma unroll
      for (int k = 0; k < CH; ++k) {
        float hk = hrow[k];
        float ahk = rlane(ah, k);
        acc += hk * w0[k] + ahk * w1[k];
      }
      float sg = sigf(acc);
      float hv = hrow[c];
      if (g == 0) Zb[(size_t)iu * CH + c] = sg;
      else        hrb[(size_t)iu * CH + c] = hv * sg;
    }
  }
}

// k2: agg(h*R) -> candidate, h update, fused FC output.
__global__ __launch_bounds__(256, 3) void k2(
    float* __restrict__ h, const float* __restrict__ hrb,
    const int* __restrict__ row_ptr, const int* __restrict__ col,
    const float* __restrict__ wgt,
    const float* __restrict__ W_hh,
    const float* __restrict__ fc_w, const float* __restrict__ fc_b,
    const float* __restrict__ Gxt, const float* __restrict__ Zb,
    float* __restrict__ outT) {
  const int lane = threadIdx.x & 63;
  const int g = lane >> 5;
  const int c = lane & 31;
  const int wid = (blockIdx.x * blockDim.x + threadIdx.x) >> 6;
  const int nw = (gridDim.x * blockDim.x) >> 6;

  float w0[CH], w1[CH], fcw[CH];
#pragma unroll
  for (int k = 0; k < CH; ++k) {
    w0[k] = W_hh[k * CH + c];
    w1[k] = W_hh[CH * CH + k * CH + c];
    fcw[k] = fc_w[k * COUT + (c & 7)];
  }
  const float fb = fc_b[c & 7];

  for (int i = wid * 2; i < NN; i += nw * 2) {
#pragma unroll
    for (int u = 0; u < 2; ++u) {
      const int iu = __builtin_amdgcn_readfirstlane(i + u);
      const int e0 = __builtin_amdgcn_readfirstlane(row_ptr[iu]);
      const int e1 = __builtin_amdgcn_readfirstlane(row_ptr[iu + 1]);
      float ahr = agg16(hrb, col, wgt, e0, e1, g, c);

      const float* hrrow = hrb + (size_t)iu * CH;
      const float* hrow = h + (size_t)iu * CH;
      float acc = Gxt[(size_t)iu * 96 + 64 + c];
#pragma unroll
      for (int k = 0; k < CH; ++k) {
        float hk = hrrow[k];
        float ahk = rlane(ahr, k);
        acc += hk * w0[k] + ahk * w1[k];
      }
      float ht = tanh_fast(acc);
      float zv = Zb[(size_t)iu * CH + c];
      float hv = hrow[c];
      float hn = zv * hv + (1.0f - zv) * ht;   // identical in both halves
      if (g == 0) h[(size_t)iu * CH + c] = hn;

      float o0 = fb, o1 = 0.f;
#pragma unroll
      for (int k = 0; k < CH; k += 2) {
        o0 += rlane(hn, k) * fcw[k];
        o1 += rlane(hn, k + 1) * fcw[k + 1];
      }
      float o = o0 + o1;
      if (lane < COUT) outT[(size_t)iu * COUT + lane] = o;
    }
  }
}

// ---------- host ----------
extern "C" void kernel_launch(void* const* d_in, const int* in_sizes, int n_in,
                              void* d_out, int out_size, void* d_ws, size_t ws_size,
                              hipStream_t stream) {
  const float* X = (const float*)d_in[0];
  const int* idx = (const int*)d_in[1];
  const float* W_xz = (const float*)d_in[2];  const float* b_xz = (const float*)d_in[3];
  const float* W_hz = (const float*)d_in[4];  const float* b_hz = (const float*)d_in[5];
  const float* W_xr = (const float*)d_in[6];  const float* b_xr = (const float*)d_in[7];
  const float* W_hr = (const float*)d_in[8];  const float* b_hr = (const float*)d_in[9];
  const float* W_xh = (const float*)d_in[10]; const float* b_xh = (const float*)d_in[11];
  const float* W_hh = (const float*)d_in[12]; const float* b_hh = (const float*)d_in[13];
  const float* fc_w = (const float*)d_in[14]; const float* fc_b = (const float*)d_in[15];
  float* out = (float*)d_out;

  char* ws = (char*)d_ws;
  size_t off = 0;
  auto alloc = [&](size_t bytes) -> void* {
    void* p = ws + off;
    off = (off + bytes + 255) & ~(size_t)255;
    return p;
  };
  int* flag = (int*)alloc(4);
  int* deg_s = (int*)alloc((size_t)NN * 4);
  int* deg_d = (int*)alloc((size_t)NN * 4);
  int* row_ptr = (int*)alloc((size_t)(NN + 1) * 4);
  int* cursor = (int*)alloc((size_t)NN * 4);
  float* dinv = (float*)alloc((size_t)NN * 4);
  int* col = (int*)alloc((size_t)EE * 4);
  float* wgt = (float*)alloc((size_t)EE * 4);
  float* h = (float*)alloc((size_t)NN * CH * 4);
  float* hrb = (float*)alloc((size_t)NN * CH * 4);
  float* Zb = (float*)alloc((size_t)NN * CH * 4);

  const size_t gx_step = (size_t)NN * 96;              // floats per t-slab
  const size_t gxall_bytes = (size_t)TT * gx_step * 4; // ~2.46 GB
  const bool full = (ws_size >= off + gxall_bytes + (1 << 20));
  float* Gx = (float*)alloc(full ? gxall_bytes : gx_step * 4);

  k_flag<<<1, 64, 0, stream>>>(idx, flag);
  k_zero_i<<<(NN + 255) / 256, 256, 0, stream>>>(deg_s, NN);
  k_zero_i<<<(NN + 255) / 256, 256, 0, stream>>>(deg_d, NN);
  k_deg<<<(EE + 255) / 256, 256, 0, stream>>>(idx, deg_s, deg_d, flag);
  k_dinv<<<(NN + 255) / 256, 256, 0, stream>>>(deg_s, dinv);
  k_scan<<<1, 1024, 0, stream>>>(deg_d, row_ptr, cursor);
  k_fill<<<(EE + 255) / 256, 256, 0, stream>>>(idx, dinv, cursor, col, wgt, flag);
  k_zero_f<<<(NN * CH + 255) / 256, 256, 0, stream>>>(h, NN * CH);

  if (full) {
    // one batched x-side pass over all (t-quad, node)
    kx_all<<<32 * 12500, 256, 0, stream>>>(X, row_ptr, col, wgt,
                                           W_xz, b_xz, b_hz, W_xr, b_xr, b_hr,
                                           W_xh, b_xh, b_hh, Gx);
  }

  const int rblocks = 6250;  // 25000 waves, 2 nodes/wave
  for (int t = 0; t < TT; ++t) {
    float* outT = out + (size_t)t * NN * COUT;
    const float* Gxt;
    if (full) {
      Gxt = Gx + (size_t)t * gx_step;
    } else {
      const float* Xt = X + (size_t)t * NN * CIN;
      kx<<<3125, 256, 0, stream>>>(Xt, row_ptr, col, wgt,
                                   W_xz, b_xz, b_hz, W_xr, b_xr, b_hr,
                                   W_xh, b_xh, b_hh, Gx);
      Gxt = Gx;
    }
    k1<<<rblocks, 256, 0, stream>>>(h, row_ptr, col, wgt, W_hz, W_hr, Gxt, Zb, hrb);
    k2<<<rblocks, 256, 0, stream>>>(h, hrb, row_ptr, col, wgt, W_hh,
                                    fc_w, fc_b, Gxt, Zb, outT);
  }
}